// Round 7
// baseline (220.845 us; speedup 1.0000x reference)
//
#include <hip/hip_runtime.h>
#include <hip/hip_bf16.h>

// Problem constants
#define B_  8
#define S_  2048
#define H_  1024
#define P_  4096
#define K_  2048   // 2*H
#define M_  32768  // B*P
#define NT_ 32     // K-tiles (BK=64)

typedef unsigned short u16;
using bf16x8 = __attribute__((ext_vector_type(8))) short;   // 8 bf16 = 4 VGPRs
using f32x4  = __attribute__((ext_vector_type(4))) float;

#define AS1 __attribute__((address_space(1)))
#define AS3 __attribute__((address_space(3)))

__device__ inline u16 f2bf(float f) {
  union { float f; unsigned u; } c; c.f = f;
  unsigned u = c.u;
  unsigned r = (u + 0x7fffu + ((u >> 16) & 1u)) >> 16;  // RNE
  return (u16)r;
}

// ---- prep 1: hidden fp32 -> bf16 ---------------------------------------
__global__ void cvt_hidden_k(const float4* __restrict__ src,
                             ushort4* __restrict__ dst, int n4) {
  int i = blockIdx.x * blockDim.x + threadIdx.x;
  int stride = gridDim.x * blockDim.x;
  for (; i < n4; i += stride) {
    float4 v = src[i];
    ushort4 o;
    o.x = f2bf(v.x); o.y = f2bf(v.y); o.z = f2bf(v.z); o.w = f2bf(v.w);
    dst[i] = o;
  }
}

// ---- prep 2: W1 (K x N fp32, k-major) -> W1T (N x K bf16) ---------------
__global__ void transp_w1_k(const float* __restrict__ w1, u16* __restrict__ w1t) {
  __shared__ float tile[32][33];
  int n0 = blockIdx.x * 32;
  int k0 = blockIdx.y * 32;
  int tx = threadIdx.x;   // 0..31
  int ty = threadIdx.y;   // 0..7
#pragma unroll
  for (int i = 0; i < 32; i += 8)
    tile[ty + i][tx] = w1[(size_t)(k0 + ty + i) * H_ + n0 + tx];
  __syncthreads();
#pragma unroll
  for (int i = 0; i < 32; i += 8)
    w1t[(size_t)(n0 + ty + i) * K_ + k0 + tx] = f2bf(tile[tx][ty + i]);
}

// ---- main fused gather-GEMM + GELU + W2 partial contraction -------------
// 256x256 tile, BK=64 (2 k-slices of 32), 8 waves (2M x 4N).
// A (gathered) in a 3-region x 32KB LDS ring, staged T+2 ahead via
// global_load_lds; B DIRECT to registers (per-ks double buffer, reloaded
// post-MFMA one tile ahead; compiler tracks its vmcnt). Two barriers per
// phase keep the m201-style lockstep, but NO manual lgkmcnt(0): plain-load
// ds_reads let the compiler emit fine-grained per-use waits so early MFMAs
// overlap late LDS-read completions. Manual counted wait: vmcnt(12) once
// per K-tile (exactly one K-tile's 4 A-stage + 8 B issues) -> A(T+1)
// guaranteed with a full-tile slack; never drains to 0 until the tail.
// 512 blocks, XCD-swizzled: each XCD gathers from one batch (4MB = one L2).
__global__ __launch_bounds__(512, 2) void gemm_k(
    const u16*  __restrict__ hidB,   // bf16 hidden [B][S][H]
    const u16*  __restrict__ w1t,    // bf16 W1^T   [N=1024][K=2048]
    const int*  __restrict__ pairs,  // int32 [B][P][2]
    const float* __restrict__ b1,
    const float2* __restrict__ w2,   // W2 rows as float2
    float*      __restrict__ part)   // [16 q][32768 m] float2
{
  __shared__ u16 lds[3 * 16384];   // 3 A-regions x 32KB = 96KB

  // XCD-aware bijective swizzle (512 % 8 == 0)
  int orig = blockIdx.x;
  int bid = (orig & 7) * 64 + (orig >> 3);
  int nt = bid & 3;
  int mt = bid >> 2;
  int n0 = nt * 256;
  int m0 = mt * 256;
  int bI = m0 >> 12;       // batch index (256 | 4096)
  int pp = m0 & 4095;

  int t = threadIdx.x;
  int w = t >> 6;          // wave 0..7
  int l = t & 63;
  int lr = l & 15;
  int lj = l >> 4;
  int wr = w >> 2;         // wave row (M): 0..1 -> 128 rows each
  int wn = w & 3;          // wave col (N): 0..3 -> 64 cols each

  // staging: source granule swizzle (involution; read applies same XOR)
  int gsrc = (l & 7) ^ ((l >> 3) & 7);

  // gather indices for the 4 staged rows: r_i = w*32 + i*8 + (l>>3)
  int2 sv[4];
#pragma unroll
  for (int i = 0; i < 4; ++i)
    sv[i] = ((const int2*)pairs)[bI * P_ + pp + w * 32 + i * 8 + (l >> 3)];

  const u16* hidBase = hidB + ((size_t)bI << 21);            // b * S_*H_
  const u16* bRowBase = w1t + (size_t)(n0 + wn * 64 + lr) * K_;

  f32x4 acc[8][4];
#pragma unroll
  for (int i = 0; i < 8; ++i)
#pragma unroll
    for (int j = 0; j < 4; ++j)
      acc[i][j] = (f32x4){0.f, 0.f, 0.f, 0.f};

  // stage A region for K-tile `tile` (4 x global_load_lds, 1KB each)
  auto STAGE = [&](int tile) {
    unsigned reg = (unsigned)(tile % 3) * 16384u;
    int k0 = tile * 64;
    int kcol = k0 & 1023;     // column within selected half-row
    int half = k0 >> 10;      // 0 -> emb1, 1 -> emb2
#pragma unroll
    for (int i = 0; i < 4; ++i) {
      int s = half ? sv[i].y : sv[i].x;
      __builtin_amdgcn_global_load_lds(
          (const AS1 void*)(hidBase + (((size_t)s) << 10) + kcol + gsrc * 8),
          (AS3 void*)&lds[reg + (unsigned)(w * 32 + i * 8) * 64u + (unsigned)l * 8u],
          16, 0, 0);
    }
  };

#define VM12 asm volatile("s_waitcnt vmcnt(12)" ::: "memory")
#define VM8  asm volatile("s_waitcnt vmcnt(8)" ::: "memory")

// load B fragments (4 x b128 plain global loads) for tile TB, k-slice KS
#define LOADB(BV, TB, KS)                                                     \
  {                                                                           \
    int kb_ = (TB) * 64 + (KS) * 32;                                          \
    _Pragma("unroll")                                                         \
    for (int ni = 0; ni < 4; ++ni)                                            \
      BV[ni] = *(const bf16x8*)(bRowBase + (size_t)ni * 16 * K_ +             \
                                kb_ + lj * 8);                                \
  }

// one phase (T, KS): {8 af ds_reads | stage | counted wait | barrier |
//   32 MFMA (compiler-scheduled lgkm waits) | reload BV for T+1 | barrier}
#define PHASEK(T, KS, BV, STAGEOP, WAITOP)                                    \
  {                                                                           \
    unsigned reg_ = (unsigned)((T) % 3) * 16384u;                             \
    bf16x8 af[2][4];                                                          \
    _Pragma("unroll")                                                         \
    for (int MH = 0; MH < 2; ++MH)                                            \
      _Pragma("unroll")                                                       \
      for (int mi = 0; mi < 4; ++mi)                                          \
        af[MH][mi] = *(const bf16x8*)&lds[reg_ +                              \
            (unsigned)(wr * 128 + MH * 64 + mi * 16 + lr) * 64u +             \
            (unsigned)((((KS) * 4 + lj) ^ (lr & 7)) * 8)];                    \
    STAGEOP;                                                                  \
    WAITOP;                                                                   \
    __builtin_amdgcn_s_barrier();                                             \
    __builtin_amdgcn_s_setprio(1);                                            \
    _Pragma("unroll")                                                         \
    for (int MH = 0; MH < 2; ++MH)                                            \
      _Pragma("unroll")                                                       \
      for (int mi = 0; mi < 4; ++mi)                                          \
        _Pragma("unroll")                                                     \
        for (int ni = 0; ni < 4; ++ni)                                        \
          acc[MH * 4 + mi][ni] = __builtin_amdgcn_mfma_f32_16x16x32_bf16(     \
              af[MH][mi], BV[ni], acc[MH * 4 + mi][ni], 0, 0, 0);             \
    __builtin_amdgcn_s_setprio(0);                                            \
    LOADB(BV, ((T) + 1 < NT_) ? (T) + 1 : NT_ - 1, KS);                       \
    __builtin_amdgcn_s_barrier();                                             \
  }

  bf16x8 bv0[4], bv1[4];

  // prologue: A(0), A(1) in flight; B(0) both halves in flight.
  STAGE(0); STAGE(1);
  LOADB(bv0, 0, 0);
  LOADB(bv1, 0, 1);
  VM12;                       // 16 outstanding -> drains A(0) only
  __builtin_amdgcn_s_barrier();

  for (int T = 0; T < NT_ - 2; ++T) {
    PHASEK(T, 0, bv0, STAGE(T + 2), VM12);
    PHASEK(T, 1, bv1, , );
  }
  PHASEK(NT_ - 2, 0, bv0, , VM8);   // drains A(31)
  PHASEK(NT_ - 2, 1, bv1, , );
  PHASEK(NT_ - 1, 0, bv0, , );
  PHASEK(NT_ - 1, 1, bv1, , );
#undef PHASEK
#undef LOADB

  // ---- fused epilogue: bias + exact GELU + W2 contraction ----
  // acc element (mi,ni,j): row = wr*128+mi*16+lj*4+j, col = wn*64+ni*16+lr
  int q = nt * 4 + wn;
  float2* pOut = (float2*)part;
#pragma unroll
  for (int mi = 0; mi < 8; ++mi) {
    float s0[4] = {0.f, 0.f, 0.f, 0.f};
    float s1[4] = {0.f, 0.f, 0.f, 0.f};
#pragma unroll
    for (int ni = 0; ni < 4; ++ni) {
      int n = n0 + wn * 64 + ni * 16 + lr;
      float bb = b1[n];
      float2 wv = w2[n];
#pragma unroll
      for (int j = 0; j < 4; ++j) {
        float x = acc[mi][ni][j] + bb;
        float g = 0.5f * x * (1.0f + erff(x * 0.70710678118654752f));
        s0[j] += g * wv.x;
        s1[j] += g * wv.y;
      }
    }
#pragma unroll
    for (int off = 1; off < 16; off <<= 1) {
#pragma unroll
      for (int j = 0; j < 4; ++j) {
        s0[j] += __shfl_xor(s0[j], off, 64);
        s1[j] += __shfl_xor(s1[j], off, 64);
      }
    }
    if (lr == 0) {
#pragma unroll
      for (int j = 0; j < 4; ++j) {
        int m = m0 + wr * 128 + mi * 16 + lj * 4 + j;
        pOut[((size_t)q << 15) + m] = make_float2(s0[j], s1[j]);
      }
    }
  }
}

// ---- final reduce over 16 partials + b2 ---------------------------------
__global__ void reduce_k(const float2* __restrict__ part,
                         const float* __restrict__ b2,
                         float2* __restrict__ out) {
  int m = blockIdx.x * blockDim.x + threadIdx.x;
  if (m >= M_) return;
  float a0 = b2[0], a1 = b2[1];
#pragma unroll
  for (int q = 0; q < 16; ++q) {
    float2 v = part[((size_t)q << 15) + m];
    a0 += v.x; a1 += v.y;
  }
  out[m] = make_float2(a0, a1);
}

extern "C" void kernel_launch(void* const* d_in, const int* in_sizes, int n_in,
                              void* d_out, int out_size, void* d_ws, size_t ws_size,
                              hipStream_t stream) {
  const float* hidden = (const float*)d_in[0];
  const int*   pairs  = (const int*)d_in[1];
  const float* W1     = (const float*)d_in[2];
  const float* b1     = (const float*)d_in[3];
  const float* W2     = (const float*)d_in[4];
  const float* b2     = (const float*)d_in[5];
  float* out = (float*)d_out;

  // ws layout: hidden_bf16 (32 MiB) | W1T_bf16 (4 MiB) | partials (4 MiB)
  u16* hidB = (u16*)d_ws;
  u16* w1t  = hidB + (size_t)B_ * S_ * H_;
  float* part = (float*)(w1t + (size_t)H_ * K_);

  int n4 = (B_ * S_ * H_) / 4;
  cvt_hidden_k<<<4096, 256, 0, stream>>>((const float4*)hidden, (ushort4*)hidB, n4);
  transp_w1_k<<<dim3(H_ / 32, K_ / 32), dim3(32, 8), 0, stream>>>(W1, w1t);
  gemm_k<<<(M_ / 256) * (H_ / 256), 512, 0, stream>>>(
      hidB, w1t, pairs, b1, (const float2*)W2, part);
  reduce_k<<<(M_ + 255) / 256, 256, 0, stream>>>(
      (const float2*)part, b2, (float2*)out);
}

// Round 8
// 178.386 us; speedup vs baseline: 1.2380x; 1.2380x over previous
//
#include <hip/hip_runtime.h>
#include <hip/hip_bf16.h>

// Problem constants
#define B_  8
#define S_  2048
#define H_  1024
#define P_  4096
#define K_  2048   // 2*H
#define M_  32768  // B*P
#define NT_ 64     // K-tiles (BK=32)

typedef unsigned short u16;
using bf16x8 = __attribute__((ext_vector_type(8))) short;   // 8 bf16 = 4 VGPRs
using f32x4  = __attribute__((ext_vector_type(4))) float;

#define AS1 __attribute__((address_space(1)))
#define AS3 __attribute__((address_space(3)))

__device__ inline u16 f2bf(float f) {
  union { float f; unsigned u; } c; c.f = f;
  unsigned u = c.u;
  unsigned r = (u + 0x7fffu + ((u >> 16) & 1u)) >> 16;  // RNE
  return (u16)r;
}

// ---- prep 1: hidden fp32 -> bf16 ---------------------------------------
__global__ void cvt_hidden_k(const float4* __restrict__ src,
                             ushort4* __restrict__ dst, int n4) {
  int i = blockIdx.x * blockDim.x + threadIdx.x;
  int stride = gridDim.x * blockDim.x;
  for (; i < n4; i += stride) {
    float4 v = src[i];
    ushort4 o;
    o.x = f2bf(v.x); o.y = f2bf(v.y); o.z = f2bf(v.z); o.w = f2bf(v.w);
    dst[i] = o;
  }
}

// ---- prep 2: W1 (K x N fp32, k-major) -> W1T (N x K bf16) ---------------
__global__ void transp_w1_k(const float* __restrict__ w1, u16* __restrict__ w1t) {
  __shared__ float tile[32][33];
  int n0 = blockIdx.x * 32;
  int k0 = blockIdx.y * 32;
  int tx = threadIdx.x;   // 0..31
  int ty = threadIdx.y;   // 0..7
#pragma unroll
  for (int i = 0; i < 32; i += 8)
    tile[ty + i][tx] = w1[(size_t)(k0 + ty + i) * H_ + n0 + tx];
  __syncthreads();
#pragma unroll
  for (int i = 0; i < 32; i += 8)
    w1t[(size_t)(n0 + ty + i) * K_ + k0 + tx] = f2bf(tile[tx][ty + i]);
}

// ---- main fused gather-GEMM + GELU + W2 partial contraction -------------
// 256x256 tile, BK=32, 8 waves (2M x 4N), ring-3 LDS (3 x (A16K|B16K) = 96KB),
// staged t+2 ahead. 2 asymmetric phases per K-tile with acc-quadrant-disjoint
// MFMA clusters (m201 mechanism): ph1 {read A-MH0(4)+B(4) | stageA(t+2) |
// bar | 16 MFMA MH0 | bar}; ph2 {read A-MH1(4) | stageB(t+2) | vmcnt(4) |
// bar | 16 MFMA MH1 | bar}. One counted wait per tile, never 0 until tail.
// 512 blocks, XCD-swizzled: each XCD gathers from one batch (4MB = one L2).
__global__ __launch_bounds__(512, 2) void gemm_k(
    const u16*  __restrict__ hidB,   // bf16 hidden [B][S][H]
    const u16*  __restrict__ w1t,    // bf16 W1^T   [N=1024][K=2048]
    const int*  __restrict__ pairs,  // int32 [B][P][2]
    const float* __restrict__ b1,
    const float2* __restrict__ w2,   // W2 rows as float2
    float*      __restrict__ part)   // [16 q][32768 m] float2
{
  __shared__ u16 lds[3 * 16384];   // ring of 3: A [256][32] | B [256][32]

#define RNG(TB) ((unsigned)((TB) % 3) * 16384u)

  // XCD-aware bijective swizzle (512 % 8 == 0)
  int orig = blockIdx.x;
  int bid = (orig & 7) * 64 + (orig >> 3);
  int nt = bid & 3;
  int mt = bid >> 2;
  int n0 = nt * 256;
  int m0 = mt * 256;
  int bI = m0 >> 12;       // batch index (256 | 4096)
  int pp = m0 & 4095;

  int t = threadIdx.x;
  int w = t >> 6;          // wave 0..7
  int l = t & 63;
  int lr = l & 15;
  int lj = l >> 4;
  int wr = w >> 2;         // wave row (M): 0..1 -> 128 rows each
  int wn = w & 3;          // wave col (N): 0..3 -> 64 cols each

  // LDS read slot (16B granule in 64B row): slot = lj ^ ((row>>1)&3),
  // and (row>>1)&3 == (l>>1)&3 for all rows this lane reads.
  int slot8 = (lj ^ ((l >> 1) & 3)) * 8;   // u16 offset
  // staging source granule (write side of the same involution)
  int gsrc = (l & 3) ^ ((l >> 3) & 3);

  // staging rows owned by this thread (2 rows per region, 2 gloads)
  int r0 = w * 16 + (l >> 2);        // 0..127
  int r1 = 128 + r0;                 // 128..255

  int2 sv0 = ((const int2*)pairs)[bI * P_ + pp + r0];
  int2 sv1 = ((const int2*)pairs)[bI * P_ + pp + r1];

  const u16* hidBase = hidB + ((size_t)bI << 21);  // b * S_*H_

  f32x4 acc[8][4];
#pragma unroll
  for (int i = 0; i < 8; ++i)
#pragma unroll
    for (int j = 0; j < 4; ++j)
      acc[i][j] = (f32x4){0.f, 0.f, 0.f, 0.f};

  // stage A region of tile TB (2 x global_load_lds, 8KB each wave-group)
  auto STAGE_Aop = [&](int TB) {
    unsigned base = RNG(TB);
    int k0 = TB * 32;
    int kcol = k0 & 1023;
    int half = k0 >> 10;
    int sA0 = half ? sv0.y : sv0.x;
    int sA1 = half ? sv1.y : sv1.x;
    unsigned dst = base + (unsigned)(w * 512 + l * 8);
    __builtin_amdgcn_global_load_lds(
        (const AS1 void*)(hidBase + (((size_t)sA0) << 10) + kcol + gsrc * 8),
        (AS3 void*)&lds[dst], 16, 0, 0);
    __builtin_amdgcn_global_load_lds(
        (const AS1 void*)(hidBase + (((size_t)sA1) << 10) + kcol + gsrc * 8),
        (AS3 void*)&lds[dst + 4096], 16, 0, 0);
  };
  // stage B region of tile TB
  auto STAGE_Bop = [&](int TB) {
    unsigned base = RNG(TB) + 8192u;
    int k0 = TB * 32;
    unsigned dst = base + (unsigned)(w * 512 + l * 8);
    __builtin_amdgcn_global_load_lds(
        (const AS1 void*)(w1t + (size_t)(n0 + r0) * K_ + k0 + gsrc * 8),
        (AS3 void*)&lds[dst], 16, 0, 0);
    __builtin_amdgcn_global_load_lds(
        (const AS1 void*)(w1t + (size_t)(n0 + r1) * K_ + k0 + gsrc * 8),
        (AS3 void*)&lds[dst + 4096], 16, 0, 0);
  };

#define VM4 asm volatile("s_waitcnt vmcnt(4)" ::: "memory")
#define VM0 asm volatile("s_waitcnt vmcnt(0)" ::: "memory")

// one K-tile = 2 asymmetric, acc-disjoint phases
#define TILEBODY(T, STA, STB, WAITOP)                                          \
  {                                                                            \
    unsigned rg_ = RNG(T);                                                     \
    bf16x8 bv[4], af[4];                                                       \
    /* ---- ph1: A-MH0 + B reads, stage A(t+2), MFMA quadrant MH0 ---- */      \
    _Pragma("unroll")                                                          \
    for (int mi = 0; mi < 4; ++mi)                                             \
      af[mi] = *(const bf16x8*)&lds[rg_ +                                      \
          (unsigned)(wr * 128 + mi * 16 + lr) * 32u + slot8];                  \
    _Pragma("unroll")                                                          \
    for (int ni = 0; ni < 4; ++ni)                                             \
      bv[ni] = *(const bf16x8*)&lds[rg_ + 8192u +                              \
          (unsigned)(wn * 64 + ni * 16 + lr) * 32u + slot8];                   \
    STA;                                                                       \
    __builtin_amdgcn_s_barrier();                                              \
    __builtin_amdgcn_s_setprio(1);                                             \
    _Pragma("unroll")                                                          \
    for (int mi = 0; mi < 4; ++mi)                                             \
      _Pragma("unroll")                                                        \
      for (int ni = 0; ni < 4; ++ni)                                           \
        acc[mi][ni] = __builtin_amdgcn_mfma_f32_16x16x32_bf16(                 \
            af[mi], bv[ni], acc[mi][ni], 0, 0, 0);                             \
    __builtin_amdgcn_s_setprio(0);                                             \
    __builtin_amdgcn_s_barrier();                                              \
    /* ---- ph2: A-MH1 reads, stage B(t+2), counted wait, MFMA MH1 ---- */     \
    _Pragma("unroll")                                                          \
    for (int mi = 0; mi < 4; ++mi)                                             \
      af[mi] = *(const bf16x8*)&lds[rg_ +                                      \
          (unsigned)(wr * 128 + 64 + mi * 16 + lr) * 32u + slot8];             \
    STB;                                                                       \
    WAITOP;                                                                    \
    __builtin_amdgcn_s_barrier();                                              \
    __builtin_amdgcn_s_setprio(1);                                             \
    _Pragma("unroll")                                                          \
    for (int mi = 0; mi < 4; ++mi)                                             \
      _Pragma("unroll")                                                        \
      for (int ni = 0; ni < 4; ++ni)                                           \
        acc[4 + mi][ni] = __builtin_amdgcn_mfma_f32_16x16x32_bf16(             \
            af[mi], bv[ni], acc[4 + mi][ni], 0, 0, 0);                         \
    __builtin_amdgcn_s_setprio(0);                                             \
    __builtin_amdgcn_s_barrier();                                              \
  }

  // prologue: tiles 0 and 1 fully staged; wait for tile 0 (leave 1 in flight)
  STAGE_Aop(0); STAGE_Bop(0);
  STAGE_Aop(1); STAGE_Bop(1);
  VM4;
  __builtin_amdgcn_s_barrier();

  // main loop: tiles 0..61, staging t+2 (up to 63)
  for (int u = 0; u < 31; ++u) {
    int t0 = 2 * u, t1 = 2 * u + 1;
    TILEBODY(t0, STAGE_Aop(t0 + 2), STAGE_Bop(t0 + 2), VM4);
    TILEBODY(t1, STAGE_Aop(t1 + 2), STAGE_Bop(t1 + 2), VM4);
  }
  // tail: tile 62 (drain tile 63's loads), tile 63
  TILEBODY(62, , , VM0);
  TILEBODY(63, , , );
#undef TILEBODY

  // ---- fused epilogue: bias + exact GELU + W2 contraction ----
  // acc element (mi,ni,j): row = wr*128+mi*16+lj*4+j, col = wn*64+ni*16+lr
  int q = nt * 4 + wn;
  float2* pOut = (float2*)part;
#pragma unroll
  for (int mi = 0; mi < 8; ++mi) {
    float s0[4] = {0.f, 0.f, 0.f, 0.f};
    float s1[4] = {0.f, 0.f, 0.f, 0.f};
#pragma unroll
    for (int ni = 0; ni < 4; ++ni) {
      int n = n0 + wn * 64 + ni * 16 + lr;
      float bb = b1[n];
      float2 wv = w2[n];
#pragma unroll
      for (int j = 0; j < 4; ++j) {
        float x = acc[mi][ni][j] + bb;
        float g = 0.5f * x * (1.0f + erff(x * 0.70710678118654752f));
        s0[j] += g * wv.x;
        s1[j] += g * wv.y;
      }
    }
#pragma unroll
    for (int off = 1; off < 16; off <<= 1) {
#pragma unroll
      for (int j = 0; j < 4; ++j) {
        s0[j] += __shfl_xor(s0[j], off, 64);
        s1[j] += __shfl_xor(s1[j], off, 64);
      }
    }
    if (lr == 0) {
#pragma unroll
      for (int j = 0; j < 4; ++j) {
        int m = m0 + wr * 128 + mi * 16 + lj * 4 + j;
        pOut[((size_t)q << 15) + m] = make_float2(s0[j], s1[j]);
      }
    }
  }
}

// ---- final reduce over 16 partials + b2 ---------------------------------
__global__ void reduce_k(const float2* __restrict__ part,
                         const float* __restrict__ b2,
                         float2* __restrict__ out) {
  int m = blockIdx.x * blockDim.x + threadIdx.x;
  if (m >= M_) return;
  float a0 = b2[0], a1 = b2[1];
#pragma unroll
  for (int q = 0; q < 16; ++q) {
    float2 v = part[((size_t)q << 15) + m];
    a0 += v.x; a1 += v.y;
  }
  out[m] = make_float2(a0, a1);
}

extern "C" void kernel_launch(void* const* d_in, const int* in_sizes, int n_in,
                              void* d_out, int out_size, void* d_ws, size_t ws_size,
                              hipStream_t stream) {
  const float* hidden = (const float*)d_in[0];
  const int*   pairs  = (const int*)d_in[1];
  const float* W1     = (const float*)d_in[2];
  const float* b1     = (const float*)d_in[3];
  const float* W2     = (const float*)d_in[4];
  const float* b2     = (const float*)d_in[5];
  float* out = (float*)d_out;

  // ws layout: hidden_bf16 (32 MiB) | W1T_bf16 (4 MiB) | partials (4 MiB)
  u16* hidB = (u16*)d_ws;
  u16* w1t  = hidB + (size_t)B_ * S_ * H_;
  float* part = (float*)(w1t + (size_t)H_ * K_);

  int n4 = (B_ * S_ * H_) / 4;
  cvt_hidden_k<<<4096, 256, 0, stream>>>((const float4*)hidden, (ushort4*)hidB, n4);
  transp_w1_k<<<dim3(H_ / 32, K_ / 32), dim3(32, 8), 0, stream>>>(W1, w1t);
  gemm_k<<<(M_ / 256) * (H_ / 256), 512, 0, stream>>>(
      hidB, w1t, pairs, b1, (const float2*)W2, part);
  reduce_k<<<(M_ + 255) / 256, 256, 0, stream>>>(
      (const float2*)part, b2, (float2*)out);
}